// Round 8
// baseline (742.651 us; speedup 1.0000x reference)
//
#include <hip/hip_runtime.h>

typedef __attribute__((ext_vector_type(4))) float f32x4;
typedef __attribute__((ext_vector_type(2))) float f32x2;
typedef __attribute__((ext_vector_type(8))) short bf16x8;

#define NEDGE 100000
#define NNODE 10000
#define INV40f 0.15811388300841897f
#define INV120f 0.09128709291752769f

__device__ inline short f2bf(float f) {
    unsigned u = __builtin_bit_cast(unsigned, f);
    u = (u + 0x7fffu + ((u >> 16) & 1u)) >> 16;
    return (short)u;
}

__device__ __forceinline__ float bperm(int byteIdx, float v) {
    return __builtin_bit_cast(float,
        __builtin_amdgcn_ds_bpermute(byteIdx, __builtin_bit_cast(int, v)));
}

__device__ __forceinline__ void stage16(const void* gsrc, void* ldst) {
    __builtin_amdgcn_global_load_lds(
        (const __attribute__((address_space(1))) unsigned*)gsrc,
        (__attribute__((address_space(3))) unsigned*)(unsigned long long)(uintptr_t)ldst,
        16, 0, 0);
}

#define MFMA16(A,B,C) __builtin_amdgcn_mfma_f32_16x16x32_bf16((A),(B),(C),0,0,0)

// prep: fc2_w [64k][1600c] -> fc2_wt [c][k] bf16 via LDS transpose; fc1_w -> fc1_wt; zero stats+hist
__global__ __launch_bounds__(256) void prep(const float* __restrict__ fc1_w,
                                            const float* __restrict__ fc2_w,
                                            short* __restrict__ fc1_wt,
                                            short* __restrict__ fc2_wt,
                                            float* __restrict__ stats,
                                            int* __restrict__ hist) {
    const int b = blockIdx.x, t = threadIdx.x;
    if (b < 25) {
        __shared__ short tile[64 * 66];
        const int c0 = b * 64;
        #pragma unroll
        for (int rep = 0; rep < 16; rep++) {
            const int idx = rep * 256 + t;
            const int k = idx >> 6, c = idx & 63;
            tile[k * 66 + c] = f2bf(fc2_w[(size_t)k * 1600 + c0 + c]);
        }
        __syncthreads();
        #pragma unroll
        for (int rep = 0; rep < 16; rep++) {
            const int idx = rep * 256 + t;
            const int c = idx >> 6, k = idx & 63;
            fc2_wt[(size_t)(c0 + c) * 64 + k] = tile[k * 66 + c];
        }
    } else if (b == 25) {
        #pragma unroll
        for (int rep = 0; rep < 16; rep++) {
            const int i = rep * 256 + t;
            fc1_wt[(i & 63) * 64 + (i >> 6)] = f2bf(fc1_w[i]);
        }
    } else if (b == 26) {
        if (t < 72) stats[t] = 0.0f;
    } else {
        const int i = (b - 27) * 256 + t;
        if (i < NNODE) hist[i] = 0;
    }
}

// 6 waves/block, 32 edges/wave (two 16-edge groups A,B sharing each B-fragment).
// fc2_wt staged in LDS: 24KB chunks, double-buffered, XOR-swizzled. 9 phases.
__global__ __launch_bounds__(384, 3) void edge_fused(
    const float* __restrict__ node_attr,
    const float* __restrict__ edge_attr,
    const float* __restrict__ edge_sh,
    const int*   __restrict__ edge_index,
    const float* __restrict__ fc1_b,
    const float* __restrict__ fc2_b,
    const short* __restrict__ fc1_wt,
    const short* __restrict__ fc2_wt,
    float* __restrict__ tp_out,
    int*   __restrict__ hist)
{
    // LDS: cbA 24576 @0 | cbB 24576 @24576 | h_s 6x4096 @49152 | shb 6x512 @73728 = 76800
    __shared__ __align__(16) char lds[76800];
    char* cbA = lds;
    char* cbB = lds + 24576;

    const int tid  = threadIdx.x;
    const int wid  = tid >> 6;          // 0..5
    const int wtid = tid & 63;
    const int l15  = wtid & 15;
    const int lg   = wtid >> 4;
    const int lg4  = lg * 4;
    const int e0a  = blockIdx.x * 192 + wid * 32;
    const int e0b  = e0a + 16;
    const bool actA = (e0a < NEDGE);    // groups are always whole (NEDGE % 16 == 0)
    const bool actB = (e0b < NEDGE);

    char*  h_s = lds + 49152 + wid * 4096;   // [32 rows][128B] swizzled
    float* shb = (float*)(lds + 73728 + wid * 512);

#define STAGE1(CH, BUF, J) do { \
        const int _o = (wid * 4 + (J)) * 1024 + wtid * 16; \
        const int _g = _o ^ (((_o >> 7) & 7) << 4); \
        stage16((const char*)fc2_wt + (CH) * 24576 + _g, (BUF) + (wid * 4 + (J)) * 1024); \
    } while (0)
#define STAGE_FULL(CH, BUF) do { STAGE1(CH,BUF,0); STAGE1(CH,BUF,1); STAGE1(CH,BUF,2); STAGE1(CH,BUF,3); } while (0)
#define STAGE_TAIL(BUF) do { if (wid < 2) { STAGE1(8,BUF,0); STAGE1(8,BUF,1); STAGE1(8,BUF,2); STAGE1(8,BUF,3); } } while (0)

    STAGE_FULL(0, cbA);   // chunk 0 in flight; overlaps prologue

    // ---- edge meta: lanes 0..31 own one edge each ----
    int dst_r = 0;
    if (wtid < 32) {
        const int e = e0a + wtid;
        if (e < NEDGE) {
            dst_r = edge_index[NEDGE + e];
            atomicAdd(&hist[edge_index[e]], 1);
            *(f32x4*)(shb + wtid * 4) = *(const f32x4*)(edge_sh + (size_t)e * 4);
        }
    }

    // ---- fc1 A loads (clamped for inactive tail groups) ----
    const int eaA = actA ? e0a + l15 : 0;
    const int eaB = actB ? e0b + l15 : 0;
    const float* paA = edge_attr + (size_t)eaA * 64 + lg * 8;
    const float* paB = edge_attr + (size_t)eaB * 64 + lg * 8;
    const f32x4 vA0 = *(const f32x4*)(paA);
    const f32x4 vA1 = *(const f32x4*)(paA + 4);
    const f32x4 vA2 = *(const f32x4*)(paA + 32);
    const f32x4 vA3 = *(const f32x4*)(paA + 36);
    const f32x4 vB0 = *(const f32x4*)(paB);
    const f32x4 vB1 = *(const f32x4*)(paB + 4);
    const f32x4 vB2 = *(const f32x4*)(paB + 32);
    const f32x4 vB3 = *(const f32x4*)(paB + 36);

    // ---- per-lane node_attr slices ----
    const int dstA = __shfl(dst_r, l15, 64);
    const int dstB = __shfl(dst_r, 16 + l15, 64);
    const float* napA = node_attr + (size_t)dstA * 56;
    const float* napB = node_attr + (size_t)dstB * 56;
    const f32x4 xAa = *(const f32x4*)(napA + lg * 8);
    const f32x4 xAb = *(const f32x4*)(napA + lg * 8 + 4);
    const f32x2 xA1 = *(const f32x2*)(napA + 32 + lg * 6);
    const f32x2 xA2 = *(const f32x2*)(napA + 34 + lg * 6);
    const f32x2 xA3 = *(const f32x2*)(napA + 36 + lg * 6);
    const f32x4 xBa = *(const f32x4*)(napB + lg * 8);
    const f32x4 xBb = *(const f32x4*)(napB + lg * 8 + 4);
    const f32x2 xB1 = *(const f32x2*)(napB + 32 + lg * 6);
    const f32x2 xB2 = *(const f32x2*)(napB + 34 + lg * 6);
    const f32x2 xB3 = *(const f32x2*)(napB + 36 + lg * 6);
    const f32x4 shvA = *(const f32x4*)(shb + l15 * 4);        // same-wave RAW, in-order
    const f32x4 shvB = *(const f32x4*)(shb + (16 + l15) * 4);

    // ---- register coefficient tables (48 VGPR) ----
    float c00A[8], cb1A[8], c10A[6], c11A[2];
    float c00B[8], cb1B[8], c10B[6], c11B[2];
    {
        const float s0A = shvA[0], s0B = shvB[0];
        #pragma unroll
        for (int j = 0; j < 4; j++) {
            cb1A[j]   = INV40f * xAa[j];  cb1A[4+j] = INV40f * xAb[j];
            c00A[j]   = s0A * cb1A[j];    c00A[4+j] = s0A * cb1A[4+j];
            cb1B[j]   = INV40f * xBa[j];  cb1B[4+j] = INV40f * xBb[j];
            c00B[j]   = s0B * cb1B[j];    c00B[4+j] = s0B * cb1B[4+j];
        }
        const float iA = INV40f * s0A, iB = INV40f * s0B;
        c10A[0]=iA*xA1[0]; c10A[1]=iA*xA1[1]; c10A[2]=iA*xA2[0];
        c10A[3]=iA*xA2[1]; c10A[4]=iA*xA3[0]; c10A[5]=iA*xA3[1];
        c10B[0]=iB*xB1[0]; c10B[1]=iB*xB1[1]; c10B[2]=iB*xB2[0];
        c10B[3]=iB*xB2[1]; c10B[4]=iB*xB3[0]; c10B[5]=iB*xB3[1];
        c11A[0] = INV120f * (xA1[0]*shvA[1] + xA1[1]*shvA[2] + xA2[0]*shvA[3]);
        c11A[1] = INV120f * (xA2[1]*shvA[1] + xA3[0]*shvA[2] + xA3[1]*shvA[3]);
        c11B[0] = INV120f * (xB1[0]*shvB[1] + xB1[1]*shvB[2] + xB2[0]*shvB[3]);
        c11B[1] = INV120f * (xB2[1]*shvB[1] + xB3[0]*shvB[2] + xB3[1]*shvB[3]);
    }
    int vidx[4];
    #pragma unroll
    for (int g = 0; g < 4; g++) vidx[g] = (g * 16 + l15) * 4;

    // ---- fc1 for both groups -> h (relu bf16) via swizzled wave-private LDS ----
    bf16x8 aA0, aA1, aB0, aB1;
    #pragma unroll
    for (int i = 0; i < 4; i++) {
        aA0[i] = f2bf(vA0[i]); aA0[4+i] = f2bf(vA1[i]);
        aA1[i] = f2bf(vA2[i]); aA1[4+i] = f2bf(vA3[i]);
        aB0[i] = f2bf(vB0[i]); aB0[4+i] = f2bf(vB1[i]);
        aB1[i] = f2bf(vB2[i]); aB1[4+i] = f2bf(vB3[i]);
    }
    #pragma unroll
    for (int nf0 = 0; nf0 < 4; nf0++) {
        const bf16x8 b0 = *(const bf16x8*)(fc1_wt + (nf0*16 + l15)*64 + lg*8);
        const bf16x8 b1 = *(const bf16x8*)(fc1_wt + (nf0*16 + l15)*64 + 32 + lg*8);
        const float bias = fc1_b[nf0*16 + l15];
        f32x4 cA = {bias, bias, bias, bias};
        cA = MFMA16(aA0, b0, cA);
        cA = MFMA16(aA1, b1, cA);
        f32x4 cB = {bias, bias, bias, bias};
        cB = MFMA16(aB0, b0, cB);
        cB = MFMA16(aB1, b1, cB);
        #pragma unroll
        for (int reg = 0; reg < 4; reg++) {
            const int rA = lg4 + reg, rB = 16 + lg4 + reg;
            *(short*)(h_s + ((rA*128 + (nf0*16 + l15)*2) ^ ((rA & 7) << 4))) =
                f2bf(fmaxf(cA[reg], 0.0f));
            *(short*)(h_s + ((rB*128 + (nf0*16 + l15)*2) ^ ((rB & 7) << 4))) =
                f2bf(fmaxf(cB[reg], 0.0f));
        }
    }
    const int hswz = (l15 & 7) << 4;
    const bf16x8 haA0 = *(const bf16x8*)(h_s + (( l15      *128 +      lg*16) ^ hswz));
    const bf16x8 haA1 = *(const bf16x8*)(h_s + (( l15      *128 + 64 + lg*16) ^ hswz));
    const bf16x8 haB0 = *(const bf16x8*)(h_s + (((16 + l15)*128 +      lg*16) ^ hswz));
    const bf16x8 haB1 = *(const bf16x8*)(h_s + (((16 + l15)*128 + 64 + lg*16) ^ hswz));

    // ---- fc2 consume state ----
    const int ro0 = (l15 * 128 + lg * 16) ^ hswz;
    const int ro1 = (l15 * 128 + lg * 16 + 64) ^ hswz;
    const int usel = lg >> 1;
    float accA[2][4] = {{0,0,0,0},{0,0,0,0}}, accB[2][4] = {{0,0,0,0},{0,0,0,0}};
    float ab1A[4] = {0,0,0,0}, ab1B[4] = {0,0,0,0};
    float b2A[12] = {}, b2B[12] = {};

    auto cons = [&](const char* cb, int i, int nf) {
        const bf16x8 b0 = *(const bf16x8*)(cb + i * 2048 + ro0);
        const bf16x8 b1 = *(const bf16x8*)(cb + i * 2048 + ro1);
        const f32x4 cb4 = *(const f32x4*)(fc2_b + nf * 16 + lg4);
        f32x4 cA = cb4, cB = cb4;
        cA = MFMA16(b0, haA0, cA);
        cB = MFMA16(b0, haB0, cB);
        cA = MFMA16(b1, haA1, cA);
        cB = MFMA16(b1, haB1, cB);
        if (nf < 64) {                       // w00 -> out0
            const int u = nf >> 1, hi = nf & 1;
            const float cvA = bperm(vidx[u >> 3], c00A[u & 7]);
            const float cvB = bperm(vidx[u >> 3], c00B[u & 7]);
            #pragma unroll
            for (int reg = 0; reg < 4; reg++) {
                accA[hi][reg] += cvA * cA[reg];
                accB[hi][reg] += cvB * cB[reg];
            }
        } else if (nf < 80) {                // w01 -> b1
            const int nfl = nf - 64;
            const int r0 = (2 * nfl) & 7, g = nfl >> 2;
            const float eA0 = bperm(vidx[g], cb1A[r0]);
            const float eA1 = bperm(vidx[g], cb1A[r0 + 1]);
            const float eB0 = bperm(vidx[g], cb1B[r0]);
            const float eB1 = bperm(vidx[g], cb1B[r0 + 1]);
            const float cvA = usel ? eA1 : eA0;
            const float cvB = usel ? eB1 : eB0;
            #pragma unroll
            for (int reg = 0; reg < 4; reg++) {
                ab1A[reg] += cvA * cA[reg];
                ab1B[reg] += cvB * cB[reg];
            }
        } else if (nf < 84) {                // w10 -> b2
            const int nfl = nf - 80;
            #pragma unroll
            for (int k = 0; k < 3; k++) {
                const float eA0 = bperm(vidx[nfl], c10A[k]);
                const float eA1 = bperm(vidx[nfl], c10A[3 + k]);
                const float eB0 = bperm(vidx[nfl], c10B[k]);
                const float eB1 = bperm(vidx[nfl], c10B[3 + k]);
                const float cvA = usel ? eA1 : eA0;
                const float cvB = usel ? eB1 : eB0;
                #pragma unroll
                for (int reg = 0; reg < 4; reg++) {
                    b2A[reg * 3 + k] += cvA * cA[reg];
                    b2B[reg * 3 + k] += cvB * cB[reg];
                }
            }
        } else {                             // w11 -> out0
            const int ridx = nf - 84;
            const int up = ridx >> 1, hi = ridx & 1;
            const float cvA = bperm(vidx[up >> 1], c11A[up & 1]);
            const float cvB = bperm(vidx[up >> 1], c11B[up & 1]);
            #pragma unroll
            for (int reg = 0; reg < 4; reg++) {
                accA[hi][reg] += cvA * cA[reg];
                accB[hi][reg] += cvB * cB[reg];
            }
        }
    };
    auto CONS12 = [&](const char* cb, int base) {
        #pragma unroll
        for (int i = 0; i < 12; i++) cons(cb, i, base + i);
    };
    auto CONS4 = [&](const char* cb, int base) {
        #pragma unroll
        for (int i = 0; i < 4; i++) cons(cb, i, base + i);
    };

    // ---- 9-phase chunk pipeline ----
    __syncthreads();                                   // chunk 0 ready
    STAGE_FULL(1, cbB); CONS12(cbA,  0); __syncthreads();
    STAGE_FULL(2, cbA); CONS12(cbB, 12); __syncthreads();
    STAGE_FULL(3, cbB); CONS12(cbA, 24); __syncthreads();
    STAGE_FULL(4, cbA); CONS12(cbB, 36); __syncthreads();
    STAGE_FULL(5, cbB); CONS12(cbA, 48); __syncthreads();
    STAGE_FULL(6, cbA); CONS12(cbB, 60); __syncthreads();
    STAGE_FULL(7, cbB); CONS12(cbA, 72); __syncthreads();
    STAGE_TAIL(cbA);    CONS12(cbB, 84); __syncthreads();
                        CONS4 (cbA, 96);

    // ---- emit (edge-ordered, coalesced) ----
    if (actA) {
        float* orow = tp_out + (size_t)(e0a + l15) * 56;
        *(f32x4*)(orow + lg4)      = f32x4{accA[0][0], accA[0][1], accA[0][2], accA[0][3]};
        *(f32x4*)(orow + 16 + lg4) = f32x4{accA[1][0], accA[1][1], accA[1][2], accA[1][3]};
    }
    if (actB) {
        float* orow = tp_out + (size_t)(e0b + l15) * 56;
        *(f32x4*)(orow + lg4)      = f32x4{accB[0][0], accB[0][1], accB[0][2], accB[0][3]};
        *(f32x4*)(orow + 16 + lg4) = f32x4{accB[1][0], accB[1][1], accB[1][2], accB[1][3]};
    }
    #pragma unroll
    for (int reg = 0; reg < 4; reg++) {
        ab1A[reg] += __shfl_xor(ab1A[reg], 32, 64);
        ab1B[reg] += __shfl_xor(ab1B[reg], 32, 64);
    }
    #pragma unroll
    for (int m = 0; m < 12; m++) {
        b2A[m] += __shfl_xor(b2A[m], 32, 64);
        b2B[m] += __shfl_xor(b2B[m], 32, 64);
    }
    if (lg < 2) {
        if (actA) {
            float* orow = tp_out + (size_t)(e0a + l15) * 56;
            float ov[12];
            #pragma unroll
            for (int reg = 0; reg < 4; reg++) {
                ov[reg*3+0] = shvA[1]*ab1A[reg] + b2A[reg*3+0];
                ov[reg*3+1] = shvA[2]*ab1A[reg] + b2A[reg*3+1];
                ov[reg*3+2] = shvA[3]*ab1A[reg] + b2A[reg*3+2];
            }
            float* p1 = orow + 32 + lg * 12;
            *(f32x4*)(p1)     = f32x4{ov[0], ov[1], ov[2],  ov[3]};
            *(f32x4*)(p1 + 4) = f32x4{ov[4], ov[5], ov[6],  ov[7]};
            *(f32x4*)(p1 + 8) = f32x4{ov[8], ov[9], ov[10], ov[11]};
        }
        if (actB) {
            float* orow = tp_out + (size_t)(e0b + l15) * 56;
            float ov[12];
            #pragma unroll
            for (int reg = 0; reg < 4; reg++) {
                ov[reg*3+0] = shvB[1]*ab1B[reg] + b2B[reg*3+0];
                ov[reg*3+1] = shvB[2]*ab1B[reg] + b2B[reg*3+1];
                ov[reg*3+2] = shvB[3]*ab1B[reg] + b2B[reg*3+2];
            }
            float* p1 = orow + 32 + lg * 12;
            *(f32x4*)(p1)     = f32x4{ov[0], ov[1], ov[2],  ov[3]};
            *(f32x4*)(p1 + 4) = f32x4{ov[4], ov[5], ov[6],  ov[7]};
            *(f32x4*)(p1 + 8) = f32x4{ov[8], ov[9], ov[10], ov[11]};
        }
    }
#undef STAGE1
#undef STAGE_FULL
#undef STAGE_TAIL
}

// exclusive prefix scan of hist[10000] -> offsets[10001], cursor
__global__ __launch_bounds__(1024) void scan_hist(const int* __restrict__ hist,
                                                  int* __restrict__ offsets,
                                                  int* __restrict__ cursor) {
    __shared__ int part[1024];
    const int t = threadIdx.x;
    const int n0 = t * 10;
    int lh[10];
    int s = 0;
    if (n0 < NNODE) {
        #pragma unroll
        for (int j = 0; j < 10; j++) { lh[j] = hist[n0 + j]; s += lh[j]; }
    }
    part[t] = s;
    __syncthreads();
    for (int d = 1; d < 1024; d <<= 1) {
        const int v = (t >= d) ? part[t - d] : 0;
        __syncthreads();
        part[t] += v;
        __syncthreads();
    }
    if (n0 < NNODE) {
        int run = part[t] - s;
        #pragma unroll
        for (int j = 0; j < 10; j++) {
            offsets[n0 + j] = run; cursor[n0 + j] = run; run += lh[j];
        }
    }
    if (t == 0) offsets[NNODE] = NEDGE;
}

__global__ __launch_bounds__(256) void fill_perm(const int* __restrict__ edge_index,
                                                 int* __restrict__ cursor,
                                                 int* __restrict__ perm) {
    const int e = blockIdx.x * 256 + threadIdx.x;
    if (e < NEDGE) {
        const int s = edge_index[e];
        const int p = atomicAdd(&cursor[s], 1);
        perm[p] = e;
    }
}

// gather-based segment mean + residual + BN partial stats
__global__ __launch_bounds__(256) void node_agg(
    const float* __restrict__ tp_out, const int* __restrict__ offsets,
    const int* __restrict__ perm,
    const float* __restrict__ node_attr, float* __restrict__ out,
    float* __restrict__ stats)
{
    __shared__ float part[72];
    const int tid = threadIdx.x;
    if (tid < 72) part[tid] = 0.0f;
    __syncthreads();
    const int n = blockIdx.x * 16 + (tid >> 4);
    const int q = tid & 15;
    if (n < NNODE && q < 14) {
        const int st = offsets[n], en = offsets[n + 1];
        f32x4 acc = {0.f, 0.f, 0.f, 0.f};
        for (int r = st; r < en; r++)
            acc += *(const f32x4*)(tp_out + (size_t)perm[r] * 56 + q * 4);
        const float inv = 1.0f / fmaxf((float)(en - st), 1.0f);
        const int c0 = q * 4;
        const f32x4 res = *(const f32x4*)(node_attr + (size_t)n * 56 + c0);
        f32x4 val;
        #pragma unroll
        for (int j = 0; j < 4; j++) {
            val[j] = acc[j] * inv + res[j];
            const int c = c0 + j;
            if (c < 32) {
                atomicAdd(&part[c], val[j]);
                atomicAdd(&part[32 + c], val[j] * val[j]);
            } else {
                atomicAdd(&part[64 + (c - 32) / 3], val[j] * val[j]);
            }
        }
        *(f32x4*)(out + (size_t)n * 56 + c0) = val;
    }
    __syncthreads();
    if (tid < 72) unsafeAtomicAdd(&stats[tid], part[tid]);
}

__global__ __launch_bounds__(256) void node_norm(
    float* __restrict__ out, const float* __restrict__ stats,
    const float* __restrict__ g0, const float* __restrict__ b0,
    const float* __restrict__ g1)
{
    const int id = blockIdx.x * 256 + threadIdx.x;
    if (id >= NNODE * 56) return;
    const int c = id % 56;
    float val = out[id];
    if (c < 32) {
        const float m   = stats[c]      * (1.0f / NNODE);
        const float ex2 = stats[32 + c] * (1.0f / NNODE);
        const float var = ex2 - m * m;
        val = (val - m) * rsqrtf(var + 1e-5f) * g0[c] + b0[c];
    } else {
        const int v = (c - 32) / 3;
        const float vn = stats[64 + v] * (1.0f / (3.0f * NNODE));
        val = val * rsqrtf(vn + 1e-5f) * g1[v];
    }
    out[id] = val;
}

extern "C" void kernel_launch(void* const* d_in, const int* in_sizes, int n_in,
                              void* d_out, int out_size, void* d_ws, size_t ws_size,
                              hipStream_t stream) {
    const float* node_attr = (const float*)d_in[0];
    const float* edge_attr = (const float*)d_in[1];
    const float* edge_sh   = (const float*)d_in[2];
    const int*   edge_index= (const int*)  d_in[3];
    const float* fc1_w     = (const float*)d_in[4];
    const float* fc1_b     = (const float*)d_in[5];
    const float* fc2_w     = (const float*)d_in[6];
    const float* fc2_b     = (const float*)d_in[7];
    const float* g0        = (const float*)d_in[8];
    const float* b0        = (const float*)d_in[9];
    const float* g1        = (const float*)d_in[10];
    float* out = (float*)d_out;

    char* ws = (char*)d_ws;
    float* stats   = (float*)(ws + 0);
    int*   hist    = (int*)  (ws + 288);
    int*   offsets = (int*)  (ws + 40288);
    int*   cursor  = (int*)  (ws + 80320);
    int*   perm    = (int*)  (ws + 120320);
    short* fc1_wt  = (short*)(ws + 520320);
    short* fc2_wt  = (short*)(ws + 528512);
    float* tp_out  = (float*)(ws + 733312);

    prep<<<67, 256, 0, stream>>>(fc1_w, fc2_w, fc1_wt, fc2_wt, stats, hist);
    edge_fused<<<521, 384, 0, stream>>>(node_attr, edge_attr, edge_sh, edge_index,
                                        fc1_b, fc2_b, fc1_wt, fc2_wt, tp_out, hist);
    scan_hist<<<1, 1024, 0, stream>>>(hist, offsets, cursor);
    fill_perm<<<391, 256, 0, stream>>>(edge_index, cursor, perm);
    node_agg<<<625, 256, 0, stream>>>(tp_out, offsets, perm, node_attr, out, stats);
    node_norm<<<2188, 256, 0, stream>>>(out, stats, g0, b0, g1);
}

// Round 9
// 442.483 us; speedup vs baseline: 1.6784x; 1.6784x over previous
//
#include <hip/hip_runtime.h>

typedef __attribute__((ext_vector_type(4))) float f32x4;
typedef __attribute__((ext_vector_type(2))) float f32x2;
typedef __attribute__((ext_vector_type(8))) short bf16x8;

#define NEDGE 100000
#define NNODE 10000
#define INV40f 0.15811388300841897f
#define INV120f 0.09128709291752769f

__device__ inline short f2bf(float f) {
    unsigned u = __builtin_bit_cast(unsigned, f);
    u = (u + 0x7fffu + ((u >> 16) & 1u)) >> 16;
    return (short)u;
}

__device__ __forceinline__ float bperm(int byteIdx, float v) {
    return __builtin_bit_cast(float,
        __builtin_amdgcn_ds_bpermute(byteIdx, __builtin_bit_cast(int, v)));
}

__device__ __forceinline__ void stage16(const void* gsrc, void* ldst) {
    __builtin_amdgcn_global_load_lds(
        (const __attribute__((address_space(1))) unsigned*)gsrc,
        (__attribute__((address_space(3))) unsigned*)(unsigned long long)(uintptr_t)ldst,
        16, 0, 0);
}

#define MFMA16(A,B,C) __builtin_amdgcn_mfma_f32_16x16x32_bf16((A),(B),(C),0,0,0)

// prep: fc2_w [64k][1600c] -> fc2_wt [c][k] bf16 via LDS transpose; fc1_w -> fc1_wt; zero stats+hist
__global__ __launch_bounds__(256) void prep(const float* __restrict__ fc1_w,
                                            const float* __restrict__ fc2_w,
                                            short* __restrict__ fc1_wt,
                                            short* __restrict__ fc2_wt,
                                            float* __restrict__ stats,
                                            int* __restrict__ hist) {
    const int b = blockIdx.x, t = threadIdx.x;
    if (b < 25) {
        __shared__ short tile[64 * 66];
        const int c0 = b * 64;
        #pragma unroll
        for (int rep = 0; rep < 16; rep++) {
            const int idx = rep * 256 + t;
            const int k = idx >> 6, c = idx & 63;
            tile[k * 66 + c] = f2bf(fc2_w[(size_t)k * 1600 + c0 + c]);
        }
        __syncthreads();
        #pragma unroll
        for (int rep = 0; rep < 16; rep++) {
            const int idx = rep * 256 + t;
            const int c = idx >> 6, k = idx & 63;
            fc2_wt[(size_t)(c0 + c) * 64 + k] = tile[k * 66 + c];
        }
    } else if (b == 25) {
        #pragma unroll
        for (int rep = 0; rep < 16; rep++) {
            const int i = rep * 256 + t;
            fc1_wt[(i & 63) * 64 + (i >> 6)] = f2bf(fc1_w[i]);
        }
    } else if (b == 26) {
        if (t < 72) stats[t] = 0.0f;
    } else {
        const int i = (b - 27) * 256 + t;
        if (i < NNODE) hist[i] = 0;
    }
}

// 4 waves/block, 32 edges/wave (two 16-edge groups A,B sharing every B-fragment read).
// fc2_wt staged in LDS: 13 x 16KB chunks, double-buffered, XOR-swizzled.
__global__ __launch_bounds__(256, 2) void edge_fused(
    const float* __restrict__ node_attr,
    const float* __restrict__ edge_attr,
    const float* __restrict__ edge_sh,
    const int*   __restrict__ edge_index,
    const float* __restrict__ fc1_b,
    const float* __restrict__ fc2_b,
    const short* __restrict__ fc1_wt,
    const short* __restrict__ fc2_wt,
    float* __restrict__ tp_out,
    int*   __restrict__ hist)
{
    // LDS: cbA 16384 @0 | cbB 16384 @16384 | h_s 4x4096 @32768 | shb 4x512 @49152 = 51200
    __shared__ __align__(16) char lds[51200];
    char* cbA = lds;
    char* cbB = lds + 16384;

    const int tid  = threadIdx.x;
    const int wid  = tid >> 6;          // 0..3
    const int wtid = tid & 63;
    const int l15  = wtid & 15;
    const int lg   = wtid >> 4;
    const int lg4  = lg * 4;
    const int e0a  = blockIdx.x * 128 + wid * 32;
    const int e0b  = e0a + 16;
    const bool actA = (e0a < NEDGE);    // groups always whole (NEDGE % 16 == 0)
    const bool actB = (e0b < NEDGE);

    char*  h_s = lds + 32768 + wid * 4096;   // [32 rows][128B] swizzled
    float* shb = (float*)(lds + 49152 + wid * 512);

#define STAGE1(CH, BUF, J) do { \
        const int _o = (wid * 4 + (J)) * 1024 + wtid * 16; \
        const int _g = _o ^ (((_o >> 7) & 7) << 4); \
        stage16((const char*)fc2_wt + (CH) * 16384 + _g, (BUF) + (wid * 4 + (J)) * 1024); \
    } while (0)
#define STAGE_FULL(CH, BUF) do { STAGE1(CH,BUF,0); STAGE1(CH,BUF,1); STAGE1(CH,BUF,2); STAGE1(CH,BUF,3); } while (0)
#define STAGE_TAIL(BUF) do { if (wid < 2) { STAGE1(12,BUF,0); STAGE1(12,BUF,1); STAGE1(12,BUF,2); STAGE1(12,BUF,3); } } while (0)

    STAGE_FULL(0, cbA);   // chunk 0 in flight; overlaps prologue

    // ---- edge meta: lanes 0..31 own one edge each ----
    int dst_r = 0;
    if (wtid < 32) {
        const int e = e0a + wtid;
        if (e < NEDGE) {
            dst_r = edge_index[NEDGE + e];
            atomicAdd(&hist[edge_index[e]], 1);
            *(f32x4*)(shb + wtid * 4) = *(const f32x4*)(edge_sh + (size_t)e * 4);
        }
    }

    // ---- fc1 A loads (clamped for inactive tail groups) ----
    const int eaA = actA ? e0a + l15 : 0;
    const int eaB = actB ? e0b + l15 : 0;
    const float* paA = edge_attr + (size_t)eaA * 64 + lg * 8;
    const float* paB = edge_attr + (size_t)eaB * 64 + lg * 8;
    const f32x4 vA0 = *(const f32x4*)(paA);
    const f32x4 vA1 = *(const f32x4*)(paA + 4);
    const f32x4 vA2 = *(const f32x4*)(paA + 32);
    const f32x4 vA3 = *(const f32x4*)(paA + 36);
    const f32x4 vB0 = *(const f32x4*)(paB);
    const f32x4 vB1 = *(const f32x4*)(paB + 4);
    const f32x4 vB2 = *(const f32x4*)(paB + 32);
    const f32x4 vB3 = *(const f32x4*)(paB + 36);

    // ---- per-lane node_attr slices ----
    const int dstA = __shfl(dst_r, l15, 64);
    const int dstB = __shfl(dst_r, 16 + l15, 64);
    const float* napA = node_attr + (size_t)dstA * 56;
    const float* napB = node_attr + (size_t)dstB * 56;
    const f32x4 xAa = *(const f32x4*)(napA + lg * 8);
    const f32x4 xAb = *(const f32x4*)(napA + lg * 8 + 4);
    const f32x2 xA1 = *(const f32x2*)(napA + 32 + lg * 6);
    const f32x2 xA2 = *(const f32x2*)(napA + 34 + lg * 6);
    const f32x2 xA3 = *(const f32x2*)(napA + 36 + lg * 6);
    const f32x4 xBa = *(const f32x4*)(napB + lg * 8);
    const f32x4 xBb = *(const f32x4*)(napB + lg * 8 + 4);
    const f32x2 xB1 = *(const f32x2*)(napB + 32 + lg * 6);
    const f32x2 xB2 = *(const f32x2*)(napB + 34 + lg * 6);
    const f32x2 xB3 = *(const f32x2*)(napB + 36 + lg * 6);
    const f32x4 shvA = *(const f32x4*)(shb + l15 * 4);        // same-wave RAW, in-order
    const f32x4 shvB = *(const f32x4*)(shb + (16 + l15) * 4);

    // ---- register coefficient tables (48 VGPR) ----
    float c00A[8], cb1A[8], c10A[6], c11A[2];
    float c00B[8], cb1B[8], c10B[6], c11B[2];
    {
        const float s0A = shvA[0], s0B = shvB[0];
        #pragma unroll
        for (int j = 0; j < 4; j++) {
            cb1A[j]   = INV40f * xAa[j];  cb1A[4+j] = INV40f * xAb[j];
            c00A[j]   = s0A * cb1A[j];    c00A[4+j] = s0A * cb1A[4+j];
            cb1B[j]   = INV40f * xBa[j];  cb1B[4+j] = INV40f * xBb[j];
            c00B[j]   = s0B * cb1B[j];    c00B[4+j] = s0B * cb1B[4+j];
        }
        const float iA = INV40f * s0A, iB = INV40f * s0B;
        c10A[0]=iA*xA1[0]; c10A[1]=iA*xA1[1]; c10A[2]=iA*xA2[0];
        c10A[3]=iA*xA2[1]; c10A[4]=iA*xA3[0]; c10A[5]=iA*xA3[1];
        c10B[0]=iB*xB1[0]; c10B[1]=iB*xB1[1]; c10B[2]=iB*xB2[0];
        c10B[3]=iB*xB2[1]; c10B[4]=iB*xB3[0]; c10B[5]=iB*xB3[1];
        c11A[0] = INV120f * (xA1[0]*shvA[1] + xA1[1]*shvA[2] + xA2[0]*shvA[3]);
        c11A[1] = INV120f * (xA2[1]*shvA[1] + xA3[0]*shvA[2] + xA3[1]*shvA[3]);
        c11B[0] = INV120f * (xB1[0]*shvB[1] + xB1[1]*shvB[2] + xB2[0]*shvB[3]);
        c11B[1] = INV120f * (xB2[1]*shvB[1] + xB3[0]*shvB[2] + xB3[1]*shvB[3]);
    }
    int vidx[4];
    #pragma unroll
    for (int g = 0; g < 4; g++) vidx[g] = (g * 16 + l15) * 4;

    // ---- fc1 for both groups -> h (relu bf16) via swizzled wave-private LDS ----
    bf16x8 aA0, aA1, aB0, aB1;
    #pragma unroll
    for (int i = 0; i < 4; i++) {
        aA0[i] = f2bf(vA0[i]); aA0[4+i] = f2bf(vA1[i]);
        aA1[i] = f2bf(vA2[i]); aA1[4+i] = f2bf(vA3[i]);
        aB0[i] = f2bf(vB0[i]); aB0[4+i] = f2bf(vB1[i]);
        aB1[i] = f2bf(vB2[i]); aB1[4+i] = f2bf(vB3[i]);
    }
    #pragma unroll
    for (int nf0 = 0; nf0 < 4; nf0++) {
        const bf16x8 b0 = *(const bf16x8*)(fc1_wt + (nf0*16 + l15)*64 + lg*8);
        const bf16x8 b1 = *(const bf16x8*)(fc1_wt + (nf0*16 + l15)*64 + 32 + lg*8);
        const float bias = fc1_b[nf0*16 + l15];
        f32x4 cA = {bias, bias, bias, bias};
        cA = MFMA16(aA0, b0, cA);
        cA = MFMA16(aA1, b1, cA);
        f32x4 cB = {bias, bias, bias, bias};
        cB = MFMA16(aB0, b0, cB);
        cB = MFMA16(aB1, b1, cB);
        #pragma unroll
        for (int reg = 0; reg < 4; reg++) {
            const int rA = lg4 + reg, rB = 16 + lg4 + reg;
            *(short*)(h_s + ((rA*128 + (nf0*16 + l15)*2) ^ ((rA & 7) << 4))) =
                f2bf(fmaxf(cA[reg], 0.0f));
            *(short*)(h_s + ((rB*128 + (nf0*16 + l15)*2) ^ ((rB & 7) << 4))) =
                f2bf(fmaxf(cB[reg], 0.0f));
        }
    }
    const int hswz = (l15 & 7) << 4;
    const bf16x8 haA0 = *(const bf16x8*)(h_s + (( l15      *128 +      lg*16) ^ hswz));
    const bf16x8 haA1 = *(const bf16x8*)(h_s + (( l15      *128 + 64 + lg*16) ^ hswz));
    const bf16x8 haB0 = *(const bf16x8*)(h_s + (((16 + l15)*128 +      lg*16) ^ hswz));
    const bf16x8 haB1 = *(const bf16x8*)(h_s + (((16 + l15)*128 + 64 + lg*16) ^ hswz));

    // ---- fc2 consume state ----
    const int ro0 = (l15 * 128 + lg * 16) ^ hswz;
    const int ro1 = (l15 * 128 + lg * 16 + 64) ^ hswz;
    const int usel = lg >> 1;
    float accA[2][4] = {{0,0,0,0},{0,0,0,0}}, accB[2][4] = {{0,0,0,0},{0,0,0,0}};
    float ab1A[4] = {0,0,0,0}, ab1B[4] = {0,0,0,0};
    float b2A[12] = {}, b2B[12] = {};

    // R7-style per-region consumers (small, provably-unrollable shapes), group A+B inside.
    auto cons_w00 = [&](const char* cb, int ch) {
        #pragma unroll
        for (int nfl = 0; nfl < 8; nfl++) {
            const int nf = ch * 8 + nfl;
            const bf16x8 b0 = *(const bf16x8*)(cb + nfl * 2048 + ro0);
            const bf16x8 b1 = *(const bf16x8*)(cb + nfl * 2048 + ro1);
            const f32x4 cbi = *(const f32x4*)(fc2_b + nf * 16 + lg4);
            f32x4 cA = cbi, cB = cbi;
            cA = MFMA16(b0, haA0, cA);  cB = MFMA16(b0, haB0, cB);
            cA = MFMA16(b1, haA1, cA);  cB = MFMA16(b1, haB1, cB);
            const int u = nf >> 1, hi = nf & 1;
            const float cvA = bperm(vidx[u >> 3], c00A[u & 7]);
            const float cvB = bperm(vidx[u >> 3], c00B[u & 7]);
            #pragma unroll
            for (int reg = 0; reg < 4; reg++) {
                accA[hi][reg] += cvA * cA[reg];
                accB[hi][reg] += cvB * cB[reg];
            }
        }
    };
    auto cons_w01 = [&](const char* cb, int rbase) {
        #pragma unroll
        for (int i = 0; i < 8; i++) {
            const int nfl_r = rbase + i;                 // region-local 0..15
            const int nf = 64 + nfl_r;
            const bf16x8 b0 = *(const bf16x8*)(cb + i * 2048 + ro0);
            const bf16x8 b1 = *(const bf16x8*)(cb + i * 2048 + ro1);
            const f32x4 cbi = *(const f32x4*)(fc2_b + nf * 16 + lg4);
            f32x4 cA = cbi, cB = cbi;
            cA = MFMA16(b0, haA0, cA);  cB = MFMA16(b0, haB0, cB);
            cA = MFMA16(b1, haA1, cA);  cB = MFMA16(b1, haB1, cB);
            const int r0 = (2 * nfl_r) & 7, g = nfl_r >> 2;
            const float eA0 = bperm(vidx[g], cb1A[r0]);
            const float eA1 = bperm(vidx[g], cb1A[r0 + 1]);
            const float eB0 = bperm(vidx[g], cb1B[r0]);
            const float eB1 = bperm(vidx[g], cb1B[r0 + 1]);
            const float cvA = usel ? eA1 : eA0;
            const float cvB = usel ? eB1 : eB0;
            #pragma unroll
            for (int reg = 0; reg < 4; reg++) {
                ab1A[reg] += cvA * cA[reg];
                ab1B[reg] += cvB * cB[reg];
            }
        }
    };
    auto cons_w10 = [&](const char* cb, int fb) {        // 4 frags at frag-local fb
        #pragma unroll
        for (int nfl = 0; nfl < 4; nfl++) {
            const int nf = 80 + nfl;
            const bf16x8 b0 = *(const bf16x8*)(cb + (fb + nfl) * 2048 + ro0);
            const bf16x8 b1 = *(const bf16x8*)(cb + (fb + nfl) * 2048 + ro1);
            const f32x4 cbi = *(const f32x4*)(fc2_b + nf * 16 + lg4);
            f32x4 cA = cbi, cB = cbi;
            cA = MFMA16(b0, haA0, cA);  cB = MFMA16(b0, haB0, cB);
            cA = MFMA16(b1, haA1, cA);  cB = MFMA16(b1, haB1, cB);
            #pragma unroll
            for (int k = 0; k < 3; k++) {
                const float eA0 = bperm(vidx[nfl], c10A[k]);
                const float eA1 = bperm(vidx[nfl], c10A[3 + k]);
                const float eB0 = bperm(vidx[nfl], c10B[k]);
                const float eB1 = bperm(vidx[nfl], c10B[3 + k]);
                const float cvA = usel ? eA1 : eA0;
                const float cvB = usel ? eB1 : eB0;
                #pragma unroll
                for (int reg = 0; reg < 4; reg++) {
                    b2A[reg * 3 + k] += cvA * cA[reg];
                    b2B[reg * 3 + k] += cvB * cB[reg];
                }
            }
        }
    };
    auto cons_w11_4 = [&](const char* cb, int fb, int ridx0) {
        #pragma unroll
        for (int i = 0; i < 4; i++) {
            const int ridx = ridx0 + i;                  // region-local 0..15
            const int nf = 84 + ridx;
            const bf16x8 b0 = *(const bf16x8*)(cb + (fb + i) * 2048 + ro0);
            const bf16x8 b1 = *(const bf16x8*)(cb + (fb + i) * 2048 + ro1);
            const f32x4 cbi = *(const f32x4*)(fc2_b + nf * 16 + lg4);
            f32x4 cA = cbi, cB = cbi;
            cA = MFMA16(b0, haA0, cA);  cB = MFMA16(b0, haB0, cB);
            cA = MFMA16(b1, haA1, cA);  cB = MFMA16(b1, haB1, cB);
            const int up = ridx >> 1, hi = ridx & 1;
            const float cvA = bperm(vidx[up >> 1], c11A[up & 1]);
            const float cvB = bperm(vidx[up >> 1], c11B[up & 1]);
            #pragma unroll
            for (int reg = 0; reg < 4; reg++) {
                accA[hi][reg] += cvA * cA[reg];
                accB[hi][reg] += cvB * cB[reg];
            }
        }
    };

    // ---- 13-phase chunk pipeline (R7 schedule) ----
    __syncthreads();                                   // chunk 0 ready
    STAGE_FULL(1,  cbB); cons_w00(cbA, 0); __syncthreads();
    STAGE_FULL(2,  cbA); cons_w00(cbB, 1); __syncthreads();
    STAGE_FULL(3,  cbB); cons_w00(cbA, 2); __syncthreads();
    STAGE_FULL(4,  cbA); cons_w00(cbB, 3); __syncthreads();
    STAGE_FULL(5,  cbB); cons_w00(cbA, 4); __syncthreads();
    STAGE_FULL(6,  cbA); cons_w00(cbB, 5); __syncthreads();
    STAGE_FULL(7,  cbB); cons_w00(cbA, 6); __syncthreads();
    STAGE_FULL(8,  cbA); cons_w00(cbB, 7); __syncthreads();
    STAGE_FULL(9,  cbB); cons_w01(cbA, 0); __syncthreads();
    STAGE_FULL(10, cbA); cons_w01(cbB, 8); __syncthreads();
    STAGE_FULL(11, cbB); cons_w10(cbA, 0); cons_w11_4(cbA, 4, 0); __syncthreads();
    STAGE_TAIL(cbA);     cons_w11_4(cbB, 0, 4); cons_w11_4(cbB, 4, 8); __syncthreads();
                         cons_w11_4(cbA, 0, 12);

    // ---- emit (edge-ordered, coalesced) ----
    if (actA) {
        float* orow = tp_out + (size_t)(e0a + l15) * 56;
        *(f32x4*)(orow + lg4)      = f32x4{accA[0][0], accA[0][1], accA[0][2], accA[0][3]};
        *(f32x4*)(orow + 16 + lg4) = f32x4{accA[1][0], accA[1][1], accA[1][2], accA[1][3]};
    }
    if (actB) {
        float* orow = tp_out + (size_t)(e0b + l15) * 56;
        *(f32x4*)(orow + lg4)      = f32x4{accB[0][0], accB[0][1], accB[0][2], accB[0][3]};
        *(f32x4*)(orow + 16 + lg4) = f32x4{accB[1][0], accB[1][1], accB[1][2], accB[1][3]};
    }
    #pragma unroll
    for (int reg = 0; reg < 4; reg++) {
        ab1A[reg] += __shfl_xor(ab1A[reg], 32, 64);
        ab1B[reg] += __shfl_xor(ab1B[reg], 32, 64);
    }
    #pragma unroll
    for (int m = 0; m < 12; m++) {
        b2A[m] += __shfl_xor(b2A[m], 32, 64);
        b2B[m] += __shfl_xor(b2B[m], 32, 64);
    }
    if (lg < 2) {
        if (actA) {
            float* orow = tp_out + (size_t)(e0a + l15) * 56;
            float ov[12];
            #pragma unroll
            for (int reg = 0; reg < 4; reg++) {
                ov[reg*3+0] = shvA[1]*ab1A[reg] + b2A[reg*3+0];
                ov[reg*3+1] = shvA[2]*ab1A[reg] + b2A[reg*3+1];
                ov[reg*3+2] = shvA[3]*ab1A[reg] + b2A[reg*3+2];
            }
            float* p1 = orow + 32 + lg * 12;
            *(f32x4*)(p1)     = f32x4{ov[0], ov[1], ov[2],  ov[3]};
            *(f32x4*)(p1 + 4) = f32x4{ov[4], ov[5], ov[6],  ov[7]};
            *(f32x4*)(p1 + 8) = f32x4{ov[8], ov[9], ov[10], ov[11]};
        }
        if (actB) {
            float* orow = tp_out + (size_t)(e0b + l15) * 56;
            float ov[12];
            #pragma unroll
            for (int reg = 0; reg < 4; reg++) {
                ov[reg*3+0] = shvB[1]*ab1B[reg] + b2B[reg*3+0];
                ov[reg*3+1] = shvB[2]*ab1B[reg] + b2B[reg*3+1];
                ov[reg*3+2] = shvB[3]*ab1B[reg] + b2B[reg*3+2];
            }
            float* p1 = orow + 32 + lg * 12;
            *(f32x4*)(p1)     = f32x4{ov[0], ov[1], ov[2],  ov[3]};
            *(f32x4*)(p1 + 4) = f32x4{ov[4], ov[5], ov[6],  ov[7]};
            *(f32x4*)(p1 + 8) = f32x4{ov[8], ov[9], ov[10], ov[11]};
        }
    }
#undef STAGE1
#undef STAGE_FULL
#undef STAGE_TAIL
}

// exclusive prefix scan of hist[10000] -> offsets[10001], cursor (wave-shuffle scan, 1 barrier)
__global__ __launch_bounds__(256) void scan_hist(const int* __restrict__ hist,
                                                 int* __restrict__ offsets,
                                                 int* __restrict__ cursor) {
    __shared__ int wsum[4];
    const int t = threadIdx.x;
    const int lane = t & 63;
    const int w = t >> 6;
    const int n0 = t * 40;                 // 250 threads x 40 nodes (guarded)
    int s = 0;
    if (n0 < NNODE) {
        for (int j = 0; j < 40; j++) s += hist[n0 + j];
    }
    int incl = s;
    #pragma unroll
    for (int d = 1; d < 64; d <<= 1) {
        const int v = __shfl_up(incl, d, 64);
        if (lane >= d) incl += v;
    }
    if (lane == 63) wsum[w] = incl;
    __syncthreads();
    int base = 0;
    for (int ww = 0; ww < 4; ww++) base += (ww < w) ? wsum[ww] : 0;
    if (n0 < NNODE) {
        int run = base + incl - s;         // exclusive prefix
        for (int j = 0; j < 40; j++) {
            const int h = hist[n0 + j];
            offsets[n0 + j] = run; cursor[n0 + j] = run; run += h;
        }
    }
    if (t == 0) offsets[NNODE] = NEDGE;
}

__global__ __launch_bounds__(256) void fill_perm(const int* __restrict__ edge_index,
                                                 int* __restrict__ cursor,
                                                 int* __restrict__ perm) {
    const int e = blockIdx.x * 256 + threadIdx.x;
    if (e < NEDGE) {
        const int s = edge_index[e];
        const int p = atomicAdd(&cursor[s], 1);
        perm[p] = e;
    }
}

// gather-based segment mean + residual + BN partial stats
__global__ __launch_bounds__(256) void node_agg(
    const float* __restrict__ tp_out, const int* __restrict__ offsets,
    const int* __restrict__ perm,
    const float* __restrict__ node_attr, float* __restrict__ out,
    float* __restrict__ stats)
{
    __shared__ float part[72];
    const int tid = threadIdx.x;
    if (tid < 72) part[tid] = 0.0f;
    __syncthreads();
    const int n = blockIdx.x * 16 + (tid >> 4);
    const int q = tid & 15;
    if (n < NNODE && q < 14) {
        const int st = offsets[n], en = offsets[n + 1];
        f32x4 acc = {0.f, 0.f, 0.f, 0.f};
        for (int r = st; r < en; r++)
            acc += *(const f32x4*)(tp_out + (size_t)perm[r] * 56 + q * 4);
        const float inv = 1.0f / fmaxf((float)(en - st), 1.0f);
        const int c0 = q * 4;
        const f32x4 res = *(const f32x4*)(node_attr + (size_t)n * 56 + c0);
        f32x4 val;
        #pragma unroll
        for (int j = 0; j < 4; j++) {
            val[j] = acc[j] * inv + res[j];
            const int c = c0 + j;
            if (c < 32) {
                atomicAdd(&part[c], val[j]);
                atomicAdd(&part[32 + c], val[j] * val[j]);
            } else {
                atomicAdd(&part[64 + (c - 32) / 3], val[j] * val[j]);
            }
        }
        *(f32x4*)(out + (size_t)n * 56 + c0) = val;
    }
    __syncthreads();
    if (tid < 72) unsafeAtomicAdd(&stats[tid], part[tid]);
}

__global__ __launch_bounds__(256) void node_norm(
    float* __restrict__ out, const float* __restrict__ stats,
    const float* __restrict__ g0, const float* __restrict__ b0,
    const float* __restrict__ g1)
{
    const int id = blockIdx.x * 256 + threadIdx.x;
    if (id >= NNODE * 56) return;
    const int c = id % 56;
    float val = out[id];
    if (c < 32) {
        const float m   = stats[c]      * (1.0f / NNODE);
        const float ex2 = stats[32 + c] * (1.0f / NNODE);
        const float var = ex2 - m * m;
        val = (val - m) * rsqrtf(var + 1e-5f) * g0[c] + b0[c];
    } else {
        const int v = (c - 32) / 3;
        const float vn = stats[64 + v] * (1.0f / (3.0f * NNODE));
        val = val * rsqrtf(vn + 1e-5f) * g1[v];
    }
    out[id] = val;
}

extern "C" void kernel_launch(void* const* d_in, const int* in_sizes, int n_in,
                              void* d_out, int out_size, void* d_ws, size_t ws_size,
                              hipStream_t stream) {
    const float* node_attr = (const float*)d_in[0];
    const float* edge_attr = (const float*)d_in[1];
    const float* edge_sh   = (const float*)d_in[2];
    const int*   edge_index= (const int*)  d_in[3];
    const float* fc1_w     = (const float*)d_in[4];
    const float* fc1_b     = (const float*)d_in[5];
    const float* fc2_w     = (const float*)d_in[6];
    const float* fc2_b     = (const float*)d_in[7];
    const float* g0        = (const float*)d_in[8];
    const float* b0        = (const float*)d_in[9];
    const float* g1        = (const float*)d_in[10];
    float* out = (float*)d_out;

    char* ws = (char*)d_ws;
    float* stats   = (float*)(ws + 0);
    int*   hist    = (int*)  (ws + 288);
    int*   offsets = (int*)  (ws + 40288);
    int*   cursor  = (int*)  (ws + 80320);
    int*   perm    = (int*)  (ws + 120320);
    short* fc1_wt  = (short*)(ws + 520320);
    short* fc2_wt  = (short*)(ws + 528512);
    float* tp_out  = (float*)(ws + 733312);

    prep<<<67, 256, 0, stream>>>(fc1_w, fc2_w, fc1_wt, fc2_wt, stats, hist);
    edge_fused<<<782, 256, 0, stream>>>(node_attr, edge_attr, edge_sh, edge_index,
                                        fc1_b, fc2_b, fc1_wt, fc2_wt, tp_out, hist);
    scan_hist<<<1, 256, 0, stream>>>(hist, offsets, cursor);
    fill_perm<<<391, 256, 0, stream>>>(edge_index, cursor, perm);
    node_agg<<<625, 256, 0, stream>>>(tp_out, offsets, perm, node_attr, out, stats);
    node_norm<<<2188, 256, 0, stream>>>(out, stats, g0, b0, g1);
}

// Round 10
// 103.737 us; speedup vs baseline: 7.1590x; 4.2654x over previous
//
#include <hip/hip_runtime.h>

typedef __attribute__((ext_vector_type(4))) float f32x4;
typedef __attribute__((ext_vector_type(2))) float f32x2;
typedef __attribute__((ext_vector_type(8))) short bf16x8;

#define NEDGE 100000
#define NNODE 10000
#define INV40f 0.15811388300841897f
#define INV120f 0.09128709291752769f

__device__ inline short f2bf(float f) {
    unsigned u = __builtin_bit_cast(unsigned, f);
    u = (u + 0x7fffu + ((u >> 16) & 1u)) >> 16;
    return (short)u;
}

__device__ __forceinline__ float bperm(int byteIdx, float v) {
    return __builtin_bit_cast(float,
        __builtin_amdgcn_ds_bpermute(byteIdx, __builtin_bit_cast(int, v)));
}

__device__ __forceinline__ void stage16(const void* gsrc, void* ldst) {
    __builtin_amdgcn_global_load_lds(
        (const __attribute__((address_space(1))) unsigned*)gsrc,
        (__attribute__((address_space(3))) unsigned*)(unsigned long long)(uintptr_t)ldst,
        16, 0, 0);
}

#define MFMA16(A,B,C) __builtin_amdgcn_mfma_f32_16x16x32_bf16((A),(B),(C),0,0,0)

// prep: fc2_w [64k][1600c] -> fc2_wt [c][k] bf16 via LDS transpose; fc1_w -> fc1_wt; zero stats+hist
__global__ __launch_bounds__(256) void prep(const float* __restrict__ fc1_w,
                                            const float* __restrict__ fc2_w,
                                            short* __restrict__ fc1_wt,
                                            short* __restrict__ fc2_wt,
                                            float* __restrict__ stats,
                                            int* __restrict__ hist) {
    const int b = blockIdx.x, t = threadIdx.x;
    if (b < 25) {
        __shared__ short tile[64 * 66];
        const int c0 = b * 64;
        #pragma unroll
        for (int rep = 0; rep < 16; rep++) {
            const int idx = rep * 256 + t;
            const int k = idx >> 6, c = idx & 63;
            tile[k * 66 + c] = f2bf(fc2_w[(size_t)k * 1600 + c0 + c]);
        }
        __syncthreads();
        #pragma unroll
        for (int rep = 0; rep < 16; rep++) {
            const int idx = rep * 256 + t;
            const int c = idx >> 6, k = idx & 63;
            fc2_wt[(size_t)(c0 + c) * 64 + k] = tile[k * 66 + c];
        }
    } else if (b == 25) {
        #pragma unroll
        for (int rep = 0; rep < 16; rep++) {
            const int i = rep * 256 + t;
            fc1_wt[(i & 63) * 64 + (i >> 6)] = f2bf(fc1_w[i]);
        }
    } else if (b == 26) {
        if (t < 72) stats[t] = 0.0f;
    } else {
        const int i = (b - 27) * 256 + t;
        if (i < NNODE) hist[i] = 0;
    }
}

// 8 waves/block, 16 edges/wave (R7 structure). fc2_wt staged in LDS (13x16KB, dbuf, swizzled).
// New vs R7: fc2_b in LDS; 3-deep register pipeline of {b0,b1,bias} in every consume region.
__global__ __launch_bounds__(512, 4) void edge_fused(
    const float* __restrict__ node_attr,
    const float* __restrict__ edge_attr,
    const float* __restrict__ edge_sh,
    const int*   __restrict__ edge_index,
    const float* __restrict__ fc1_b,
    const float* __restrict__ fc2_b,
    const short* __restrict__ fc1_wt,
    const short* __restrict__ fc2_wt,
    float* __restrict__ tp_out,
    int*   __restrict__ hist)
{
    // LDS: cbA 16384 @0 | cbB 16384 @16384 | h_s 8x2048 @32768 | shb 8x256 @49152 | bias 6400 @51200
    __shared__ __align__(16) char lds[57600];
    char* cbA = lds;
    char* cbB = lds + 16384;
    float* bias_s = (float*)(lds + 51200);

    const int tid  = threadIdx.x;
    const int wid  = tid >> 6;
    const int wtid = tid & 63;
    const int l15  = wtid & 15;
    const int lg   = wtid >> 4;
    const int lg4  = lg * 4;
    const int e0   = blockIdx.x * 128 + wid * 16;
    const bool active = (e0 < NEDGE);

    char*  h_s = lds + 32768 + wid * 2048;
    float* shb = (float*)(lds + 49152 + wid * 256);

#define STAGE1(CH, BUF, J) do { \
        const int _o = (wid * 2 + (J)) * 1024 + wtid * 16; \
        const int _g = _o ^ (((_o >> 7) & 7) << 4); \
        stage16((const char*)fc2_wt + (CH) * 16384 + _g, (BUF) + (wid * 2 + (J)) * 1024); \
    } while (0)
#define STAGE_FULL(CH, BUF) do { STAGE1(CH, BUF, 0); STAGE1(CH, BUF, 1); } while (0)

    STAGE_FULL(0, cbA);   // chunk 0 in flight; overlaps whole prologue

    // ---- bias -> LDS (512 threads, 400 f32x4) ----
    if (tid < 400) {
        *(f32x4*)(bias_s + tid * 4) = *(const f32x4*)(fc2_b + tid * 4);
    }

    // ---- edge meta ----
    int dst_r = 0;
    if (active && wtid < 16) {
        dst_r = edge_index[NEDGE + e0 + wtid];
        const int src = edge_index[e0 + wtid];
        const f32x4 sh_r = *(const f32x4*)(edge_sh + (size_t)(e0 + wtid) * 4);
        atomicAdd(&hist[src], 1);
        *(f32x4*)(shb + wtid * 4) = sh_r;
    }

    bf16x8 ha0, ha1;
    f32x4 shv = {0.f, 0.f, 0.f, 0.f};
    float c00r[8], cb1r[8], c10r[6], c11r[2];
    int vidx[4];
    #pragma unroll
    for (int g = 0; g < 4; g++) vidx[g] = (g * 16 + l15) * 4;

    if (active) {
        // ---- fc1 A loads ----
        const float* pa = edge_attr + (size_t)(e0 + l15) * 64 + lg * 8;
        const f32x4 va0 = *(const f32x4*)(pa);
        const f32x4 va1 = *(const f32x4*)(pa + 4);
        const f32x4 va2 = *(const f32x4*)(pa + 32);
        const f32x4 va3 = *(const f32x4*)(pa + 36);

        // ---- per-lane table slices ----
        const int dstm = __shfl(dst_r, l15, 64);
        const float* nap = node_attr + (size_t)dstm * 56;
        const f32x4 x0a = *(const f32x4*)(nap + lg * 8);
        const f32x4 x0b = *(const f32x4*)(nap + lg * 8 + 4);
        const f32x2 x1a = *(const f32x2*)(nap + 32 + lg * 6);
        const f32x2 x1b = *(const f32x2*)(nap + 34 + lg * 6);
        const f32x2 x1c = *(const f32x2*)(nap + 36 + lg * 6);
        shv = *(const f32x4*)(shb + l15 * 4);   // same-wave LDS RAW, in-order

        const float s0 = shv[0];
        #pragma unroll
        for (int j = 0; j < 4; j++) {
            cb1r[j]     = INV40f * x0a[j];
            cb1r[4 + j] = INV40f * x0b[j];
            c00r[j]     = s0 * cb1r[j];
            c00r[4 + j] = s0 * cb1r[4 + j];
        }
        const float i40s0 = INV40f * s0;
        c10r[0] = i40s0 * x1a[0]; c10r[1] = i40s0 * x1a[1]; c10r[2] = i40s0 * x1b[0];
        c10r[3] = i40s0 * x1b[1]; c10r[4] = i40s0 * x1c[0]; c10r[5] = i40s0 * x1c[1];
        c11r[0] = INV120f * (x1a[0]*shv[1] + x1a[1]*shv[2] + x1b[0]*shv[3]);
        c11r[1] = INV120f * (x1b[1]*shv[1] + x1c[0]*shv[2] + x1c[1]*shv[3]);

        // ---- fc1 -> h (relu, bf16) via swizzled wave-private LDS transpose ----
        bf16x8 a0, a1;
        #pragma unroll
        for (int i = 0; i < 4; i++) {
            a0[i] = f2bf(va0[i]); a0[4+i] = f2bf(va1[i]);
            a1[i] = f2bf(va2[i]); a1[4+i] = f2bf(va3[i]);
        }
        #pragma unroll
        for (int nf0 = 0; nf0 < 4; nf0++) {
            const bf16x8 b0 = *(const bf16x8*)(fc1_wt + (nf0*16 + l15)*64 + lg*8);
            const bf16x8 b1 = *(const bf16x8*)(fc1_wt + (nf0*16 + l15)*64 + 32 + lg*8);
            const float bias = fc1_b[nf0*16 + l15];
            f32x4 c = {bias, bias, bias, bias};
            c = MFMA16(a0, b0, c);
            c = MFMA16(a1, b1, c);
            #pragma unroll
            for (int reg = 0; reg < 4; reg++) {
                const int row = lg4 + reg;
                *(short*)(h_s + ((row*128 + (nf0*16 + l15)*2) ^ ((row & 7) << 4))) =
                    f2bf(fmaxf(c[reg], 0.0f));
            }
        }
        ha0 = *(const bf16x8*)(h_s + ((l15*128 +      lg*16) ^ ((l15 & 7) << 4)));
        ha1 = *(const bf16x8*)(h_s + ((l15*128 + 64 + lg*16) ^ ((l15 & 7) << 4)));
    }

    // ---- fc2 consume state ----
    const int hswz = (l15 & 7) << 4;
    const int ro0 = (l15 * 128 + lg * 16) ^ hswz;
    const int ro1 = (l15 * 128 + lg * 16 + 64) ^ hswz;
    const int usel = lg >> 1;
    float acc0[2][4] = {{0,0,0,0},{0,0,0,0}};
    float ab1[4] = {0,0,0,0};
    float b2v[12] = {};

    // 3-deep {b0,b1,bias} register pipeline; all ring indices static under full unroll.
    auto cons_w00 = [&](const char* cb, int ch) {
        bf16x8 pb0[3], pb1[3]; f32x4 pc[3];
        #pragma unroll
        for (int k = 0; k < 3; k++) {
            pb0[k] = *(const bf16x8*)(cb + k * 2048 + ro0);
            pb1[k] = *(const bf16x8*)(cb + k * 2048 + ro1);
            pc[k]  = *(const f32x4*)(bias_s + (ch * 8 + k) * 16 + lg4);
        }
        #pragma unroll
        for (int i = 0; i < 8; i++) {
            const int s = i % 3;
            const bf16x8 b0 = pb0[s], b1 = pb1[s];
            f32x4 c = pc[s];
            if (i + 3 < 8) {
                pb0[s] = *(const bf16x8*)(cb + (i + 3) * 2048 + ro0);
                pb1[s] = *(const bf16x8*)(cb + (i + 3) * 2048 + ro1);
                pc[s]  = *(const f32x4*)(bias_s + (ch * 8 + i + 3) * 16 + lg4);
            }
            c = MFMA16(b0, ha0, c);
            c = MFMA16(b1, ha1, c);
            const int nf = ch * 8 + i;
            const int u = nf >> 1, hi = nf & 1;
            const float cv = bperm(vidx[u >> 3], c00r[u & 7]);
            #pragma unroll
            for (int reg = 0; reg < 4; reg++) acc0[hi][reg] += cv * c[reg];
        }
    };
    auto cons_w01 = [&](const char* cb, int rbase) {
        bf16x8 pb0[3], pb1[3]; f32x4 pc[3];
        #pragma unroll
        for (int k = 0; k < 3; k++) {
            pb0[k] = *(const bf16x8*)(cb + k * 2048 + ro0);
            pb1[k] = *(const bf16x8*)(cb + k * 2048 + ro1);
            pc[k]  = *(const f32x4*)(bias_s + (64 + rbase + k) * 16 + lg4);
        }
        #pragma unroll
        for (int i = 0; i < 8; i++) {
            const int s = i % 3;
            const bf16x8 b0 = pb0[s], b1 = pb1[s];
            f32x4 c = pc[s];
            if (i + 3 < 8) {
                pb0[s] = *(const bf16x8*)(cb + (i + 3) * 2048 + ro0);
                pb1[s] = *(const bf16x8*)(cb + (i + 3) * 2048 + ro1);
                pc[s]  = *(const f32x4*)(bias_s + (64 + rbase + i + 3) * 16 + lg4);
            }
            c = MFMA16(b0, ha0, c);
            c = MFMA16(b1, ha1, c);
            const int nfl_r = rbase + i;
            const int r0 = (2 * nfl_r) & 7, g = nfl_r >> 2;
            const float e0v = bperm(vidx[g], cb1r[r0]);
            const float e1v = bperm(vidx[g], cb1r[r0 + 1]);
            const float cv = usel ? e1v : e0v;
            #pragma unroll
            for (int reg = 0; reg < 4; reg++) ab1[reg] += cv * c[reg];
        }
    };
    auto cons_w10 = [&](const char* cb, int fb) {   // 4 frags, 2-deep
        bf16x8 pb0[2], pb1[2]; f32x4 pc[2];
        #pragma unroll
        for (int k = 0; k < 2; k++) {
            pb0[k] = *(const bf16x8*)(cb + (fb + k) * 2048 + ro0);
            pb1[k] = *(const bf16x8*)(cb + (fb + k) * 2048 + ro1);
            pc[k]  = *(const f32x4*)(bias_s + (80 + k) * 16 + lg4);
        }
        #pragma unroll
        for (int i = 0; i < 4; i++) {
            const int s = i % 2;
            const bf16x8 b0 = pb0[s], b1 = pb1[s];
            f32x4 c = pc[s];
            if (i + 2 < 4) {
                pb0[s] = *(const bf16x8*)(cb + (fb + i + 2) * 2048 + ro0);
                pb1[s] = *(const bf16x8*)(cb + (fb + i + 2) * 2048 + ro1);
                pc[s]  = *(const f32x4*)(bias_s + (80 + i + 2) * 16 + lg4);
            }
            c = MFMA16(b0, ha0, c);
            c = MFMA16(b1, ha1, c);
            #pragma unroll
            for (int k = 0; k < 3; k++) {
                const float e0v = bperm(vidx[i], c10r[k]);
                const float e1v = bperm(vidx[i], c10r[3 + k]);
                const float cv = usel ? e1v : e0v;
                #pragma unroll
                for (int reg = 0; reg < 4; reg++) b2v[reg * 3 + k] += cv * c[reg];
            }
        }
    };
    auto cons_w11_4 = [&](const char* cb, int fb, int ridx0) {   // 4 frags, 2-deep
        bf16x8 pb0[2], pb1[2]; f32x4 pc[2];
        #pragma unroll
        for (int k = 0; k < 2; k++) {
            pb0[k] = *(const bf16x8*)(cb + (fb + k) * 2048 + ro0);
            pb1[k] = *(const bf16x8*)(cb + (fb + k) * 2048 + ro1);
            pc[k]  = *(const f32x4*)(bias_s + (84 + ridx0 + k) * 16 + lg4);
        }
        #pragma unroll
        for (int i = 0; i < 4; i++) {
            const int s = i % 2;
            const bf16x8 b0 = pb0[s], b1 = pb1[s];
            f32x4 c = pc[s];
            if (i + 2 < 4) {
                pb0[s] = *(const bf16x8*)(cb + (fb + i + 2) * 2048 + ro0);
                pb1[s] = *(const bf16x8*)(cb + (fb + i + 2) * 2048 + ro1);
                pc[s]  = *(const f32x4*)(bias_s + (84 + ridx0 + i + 2) * 16 + lg4);
            }
            c = MFMA16(b0, ha0, c);
            c = MFMA16(b1, ha1, c);
            const int ridx = ridx0 + i;
            const int up = ridx >> 1, hi = ridx & 1;
            const float cv = bperm(vidx[up >> 1], c11r[up & 1]);
            #pragma unroll
            for (int reg = 0; reg < 4; reg++) acc0[hi][reg] += cv * c[reg];
        }
    };
    auto cons_w11_8 = [&](const char* cb, int ridx0) {   // 8 frags, 3-deep
        bf16x8 pb0[3], pb1[3]; f32x4 pc[3];
        #pragma unroll
        for (int k = 0; k < 3; k++) {
            pb0[k] = *(const bf16x8*)(cb + k * 2048 + ro0);
            pb1[k] = *(const bf16x8*)(cb + k * 2048 + ro1);
            pc[k]  = *(const f32x4*)(bias_s + (84 + ridx0 + k) * 16 + lg4);
        }
        #pragma unroll
        for (int i = 0; i < 8; i++) {
            const int s = i % 3;
            const bf16x8 b0 = pb0[s], b1 = pb1[s];
            f32x4 c = pc[s];
            if (i + 3 < 8) {
                pb0[s] = *(const bf16x8*)(cb + (i + 3) * 2048 + ro0);
                pb1[s] = *(const bf16x8*)(cb + (i + 3) * 2048 + ro1);
                pc[s]  = *(const f32x4*)(bias_s + (84 + ridx0 + i + 3) * 16 + lg4);
            }
            c = MFMA16(b0, ha0, c);
            c = MFMA16(b1, ha1, c);
            const int ridx = ridx0 + i;
            const int up = ridx >> 1, hi = ridx & 1;
            const float cv = bperm(vidx[up >> 1], c11r[up & 1]);
            #pragma unroll
            for (int reg = 0; reg < 4; reg++) acc0[hi][reg] += cv * c[reg];
        }
    };

    // ---- 13-phase chunk pipeline (R7 schedule; chunk 12 staged uniformly, tail 8KB unused) ----
    __syncthreads();                                   // chunk 0 ready (+ bias_s visible)
    STAGE_FULL(1,  cbB); if (active) cons_w00(cbA, 0); __syncthreads();
    STAGE_FULL(2,  cbA); if (active) cons_w00(cbB, 1); __syncthreads();
    STAGE_FULL(3,  cbB); if (active) cons_w00(cbA, 2); __syncthreads();
    STAGE_FULL(4,  cbA); if (active) cons_w00(cbB, 3); __syncthreads();
    STAGE_FULL(5,  cbB); if (active) cons_w00(cbA, 4); __syncthreads();
    STAGE_FULL(6,  cbA); if (active) cons_w00(cbB, 5); __syncthreads();
    STAGE_FULL(7,  cbB); if (active) cons_w00(cbA, 6); __syncthreads();
    STAGE_FULL(8,  cbA); if (active) cons_w00(cbB, 7); __syncthreads();
    STAGE_FULL(9,  cbB); if (active) cons_w01(cbA, 0); __syncthreads();
    STAGE_FULL(10, cbA); if (active) cons_w01(cbB, 8); __syncthreads();
    STAGE_FULL(11, cbB); if (active) { cons_w10(cbA, 0); cons_w11_4(cbA, 4, 0); } __syncthreads();
    STAGE_FULL(12, cbA); if (active) cons_w11_8(cbB, 4); __syncthreads();
                         if (active) cons_w11_4(cbA, 0, 12);

    if (!active) return;

    // ---- emit edge-ordered coalesced rows ----
    float* orow = tp_out + (size_t)(e0 + l15) * 56;
    {
        const f32x4 o0 = {acc0[0][0], acc0[0][1], acc0[0][2], acc0[0][3]};
        const f32x4 o1 = {acc0[1][0], acc0[1][1], acc0[1][2], acc0[1][3]};
        *(f32x4*)(orow + lg4)      = o0;
        *(f32x4*)(orow + 16 + lg4) = o1;
    }
    #pragma unroll
    for (int reg = 0; reg < 4; reg++) ab1[reg] += __shfl_xor(ab1[reg], 32, 64);
    #pragma unroll
    for (int m = 0; m < 12; m++) b2v[m] += __shfl_xor(b2v[m], 32, 64);
    if (lg < 2) {
        float ov[12];
        #pragma unroll
        for (int reg = 0; reg < 4; reg++) {
            ov[reg*3 + 0] = shv[1] * ab1[reg] + b2v[reg*3 + 0];
            ov[reg*3 + 1] = shv[2] * ab1[reg] + b2v[reg*3 + 1];
            ov[reg*3 + 2] = shv[3] * ab1[reg] + b2v[reg*3 + 2];
        }
        float* p1 = orow + 32 + lg * 12;
        *(f32x4*)(p1)     = f32x4{ov[0], ov[1], ov[2],  ov[3]};
        *(f32x4*)(p1 + 4) = f32x4{ov[4], ov[5], ov[6],  ov[7]};
        *(f32x4*)(p1 + 8) = f32x4{ov[8], ov[9], ov[10], ov[11]};
    }
#undef STAGE1
#undef STAGE_FULL
}

// exclusive prefix scan of hist[10000] -> offsets[10001], cursor (wave-shuffle scan)
__global__ __launch_bounds__(256) void scan_hist(const int* __restrict__ hist,
                                                 int* __restrict__ offsets,
                                                 int* __restrict__ cursor) {
    __shared__ int wsum[4];
    const int t = threadIdx.x;
    const int lane = t & 63;
    const int w = t >> 6;
    const int n0 = t * 40;
    int s = 0;
    if (n0 < NNODE) {
        for (int j = 0; j < 40; j++) s += hist[n0 + j];
    }
    int incl = s;
    #pragma unroll
    for (int d = 1; d < 64; d <<= 1) {
        const int v = __shfl_up(incl, d, 64);
        if (lane >= d) incl += v;
    }
    if (lane == 63) wsum[w] = incl;
    __syncthreads();
    int base = 0;
    for (int ww = 0; ww < 4; ww++) base += (ww < w) ? wsum[ww] : 0;
    if (n0 < NNODE) {
        int run = base + incl - s;
        for (int j = 0; j < 40; j++) {
            const int h = hist[n0 + j];
            offsets[n0 + j] = run; cursor[n0 + j] = run; run += h;
        }
    }
    if (t == 0) offsets[NNODE] = NEDGE;
}

__global__ __launch_bounds__(256) void fill_perm(const int* __restrict__ edge_index,
                                                 int* __restrict__ cursor,
                                                 int* __restrict__ perm) {
    const int e = blockIdx.x * 256 + threadIdx.x;
    if (e < NEDGE) {
        const int s = edge_index[e];
        const int p = atomicAdd(&cursor[s], 1);
        perm[p] = e;
    }
}

// gather-based segment mean + residual + BN partial stats
__global__ __launch_bounds__(256) void node_agg(
    const float* __restrict__ tp_out, const int* __restrict__ offsets,
    const int* __restrict__ perm,
    const float* __restrict__ node_attr, float* __restrict__ out,
    float* __restrict__ stats)
{
    __shared__ float part[72];
    const int tid = threadIdx.x;
    if (tid < 72) part[tid] = 0.0f;
    __syncthreads();
    const int n = blockIdx.x * 16 + (tid >> 4);
    const int q = tid & 15;
    if (n < NNODE && q < 14) {
        const int st = offsets[n], en = offsets[n + 1];
        f32x4 acc = {0.f, 0.f, 0.f, 0.f};
        for (int r = st; r < en; r++)
            acc += *(const f32x4*)(tp_out + (size_t)perm[r] * 56 + q * 4);
        const float inv = 1.0f / fmaxf((float)(en - st), 1.0f);
        const int c0 = q * 4;
        const f32x4 res = *(const f32x4*)(node_attr + (size_t)n * 56 + c0);
        f32x4 val;
        #pragma unroll
        for (int j = 0; j < 4; j++) {
            val[j] = acc[j] * inv + res[j];
            const int c = c0 + j;
            if (c < 32) {
                atomicAdd(&part[c], val[j]);
                atomicAdd(&part[32 + c], val[j] * val[j]);
            } else {
                atomicAdd(&part[64 + (c - 32) / 3], val[j] * val[j]);
            }
        }
        *(f32x4*)(out + (size_t)n * 56 + c0) = val;
    }
    __syncthreads();
    if (tid < 72) unsafeAtomicAdd(&stats[tid], part[tid]);
}

__global__ __launch_bounds__(256) void node_norm(
    float* __restrict__ out, const float* __restrict__ stats,
    const float* __restrict__ g0, const float* __restrict__ b0,
    const float* __restrict__ g1)
{
    const int id = blockIdx.x * 256 + threadIdx.x;
    if (id >= NNODE * 56) return;
    const int c = id % 56;
    float val = out[id];
    if (c < 32) {
        const float m   = stats[c]      * (1.0f / NNODE);
        const float ex2 = stats[32 + c] * (1.0f / NNODE);
        const float var = ex2 - m * m;
        val = (val - m) * rsqrtf(var + 1e-5f) * g0[c] + b0[c];
    } else {
        const int v = (c - 32) / 3;
        const float vn = stats[64 + v] * (1.0f / (3.0f * NNODE));
        val = val * rsqrtf(vn + 1e-5f) * g1[v];
    }
    out[id] = val;
}

extern "C" void kernel_launch(void* const* d_in, const int* in_sizes, int n_in,
                              void* d_out, int out_size, void* d_ws, size_t ws_size,
                              hipStream_t stream) {
    const float* node_attr = (const float*)d_in[0];
    const float* edge_attr = (const float*)d_in[1];
    const float* edge_sh   = (const float*)d_in[2];
    const int*   edge_index= (const int*)  d_in[3];
    const float* fc1_w     = (const float*)d_in[4];
    const float* fc1_b     = (const float*)d_in[5];
    const float* fc2_w     = (const float*)d_in[6];
    const float* fc2_b     = (const float*)d_in[7];
    const float* g0        = (const float*)d_in[8];
    const float* b0        = (const float*)d_in[9];
    const float* g1        = (const float*)d_in[10];
    float* out = (float*)d_out;

    char* ws = (char*)d_ws;
    float* stats   = (float*)(ws + 0);
    int*   hist    = (int*)  (ws + 288);
    int*   offsets = (int*)  (ws + 40288);
    int*   cursor  = (int*)  (ws + 80320);
    int*   perm    = (int*)  (ws + 120320);
    short* fc1_wt  = (short*)(ws + 520320);
    short* fc2_wt  = (short*)(ws + 528512);
    float* tp_out  = (float*)(ws + 733312);

    prep<<<67, 256, 0, stream>>>(fc1_w, fc2_w, fc1_wt, fc2_wt, stats, hist);
    edge_fused<<<782, 512, 0, stream>>>(node_attr, edge_attr, edge_sh, edge_index,
                                        fc1_b, fc2_b, fc1_wt, fc2_wt, tp_out, hist);
    scan_hist<<<1, 256, 0, stream>>>(hist, offsets, cursor);
    fill_perm<<<391, 256, 0, stream>>>(edge_index, cursor, perm);
    node_agg<<<625, 256, 0, stream>>>(tp_out, offsets, perm, node_attr, out, stats);
    node_norm<<<2188, 256, 0, stream>>>(out, stats, g0, b0, g1);
}